// Round 4
// baseline (114.011 us; speedup 1.0000x reference)
//
#include <hip/hip_runtime.h>

// BaseModel_3100966387783 — per-variable masked 3-layer MLP, b=8192, D=128, h=64, o=2.
//
// R4: brick layout + register-resident weights + persistent bt-loop (see R3),
// restructured for LOW REGISTER PRESSURE: 8 waves x 16 rows each (512 thr),
// so per-wave state is xf[4] (16 regs) + acc[4] (16, reused across layers)
// + weights 104 + biases 34  ->  ~182 peak, no spill at 2 waves/SIMD.
//   brick = 1 KB = 64 lanes x 16 B bf16; lane l holds
//   T[tile*16 + (l&15)][ks*32 + (l>>4)*8 + 0..7]  (one MFMA A/B fragment).
//
// brickify: fp32 -> bf16 bricks in d_ws (w0 pre-masked j==t -> 0, w2 zero-padded).
// fused_mlp: one block = (variable t, batch-group of 8 x 128-row tiles); wave w
// owns 16-row slice nt=w. Zero barriers (h bricks wave-private), h and h2 in
// separate LDS regions (no WAR stall). x frags for iter s+1 prefetched right
// after iter s's L0 consumes them. Bias via MFMA C-operand init.

typedef __bf16 bf16_t;
typedef __bf16 bf16x8 __attribute__((ext_vector_type(8)));
typedef float  f32x4  __attribute__((ext_vector_type(4)));

#define LEAKY 0.01f

// ---------------- ws brick regions (byte offsets) ----------------
#define XB_OFF   0u                  // x bricks:   64 bt x 8 nt x 4 ks = 2048 bricks
#define W0B_OFF  (2048u*1024u)       // w0 masked: 128 t x 4 it x 4 ks = 2048
#define W1B_OFF  (4096u*1024u)       // w1:        128 t x 4 it x 2 ks = 1024
#define W2B_OFF  (5120u*1024u)       // w2 pad16:  128 t x 2 ks        =  256
// total ws need: 5376 KiB

// =================== pre-kernel: fp32 -> bf16 brick-ify ===================
__global__ __launch_bounds__(256)
void brickify(const float* __restrict__ x,  const float* __restrict__ w0,
              const float* __restrict__ w1, const float* __restrict__ w2,
              unsigned char* __restrict__ ws)
{
    const int wid  = blockIdx.x * 4 + (threadIdx.x >> 6);  // one wave = one brick
    const int lane = threadIdx.x & 63;
    const int lr = lane & 15, lq = lane >> 4;

    float v[8];
    if (wid < 2048) {                        // ---- x bricks ----
        int bt = wid >> 5, rem = wid & 31, nt = rem >> 2, ks = rem & 3;
        const float* s = x + (size_t)(bt*128 + nt*16 + lr) * 128 + ks*32 + lq*8;
        const float4 a = *(const float4*)s, b = *(const float4*)(s + 4);
        v[0]=a.x; v[1]=a.y; v[2]=a.z; v[3]=a.w;
        v[4]=b.x; v[5]=b.y; v[6]=b.z; v[7]=b.w;
    } else if (wid < 4096) {                 // ---- w0 bricks (masked) ----
        int u = wid - 2048, t = u >> 4, rem = u & 15, it = rem >> 2, ks = rem & 3;
        int k0 = ks*32 + lq*8;
        const float* s = w0 + (size_t)(t*64 + it*16 + lr) * 128 + k0;
        const float4 a = *(const float4*)s, b = *(const float4*)(s + 4);
        v[0]=a.x; v[1]=a.y; v[2]=a.z; v[3]=a.w;
        v[4]=b.x; v[5]=b.y; v[6]=b.z; v[7]=b.w;
        #pragma unroll
        for (int j = 0; j < 8; ++j) if (k0 + j == t) v[j] = 0.f;
    } else if (wid < 5120) {                 // ---- w1 bricks ----
        int u = wid - 4096, t = u >> 3, rem = u & 7, it = rem >> 1, ks = rem & 1;
        const float* s = w1 + (size_t)(t*64 + it*16 + lr) * 64 + ks*32 + lq*8;
        const float4 a = *(const float4*)s, b = *(const float4*)(s + 4);
        v[0]=a.x; v[1]=a.y; v[2]=a.z; v[3]=a.w;
        v[4]=b.x; v[5]=b.y; v[6]=b.z; v[7]=b.w;
    } else {                                 // ---- w2 bricks, rows>=2 zero ----
        int u = wid - 5120, t = u >> 1, ks = u & 1;
        #pragma unroll
        for (int j = 0; j < 8; ++j) v[j] = 0.f;
        if (lr < 2) {
            const float* s = w2 + (size_t)(t*2 + lr) * 64 + ks*32 + lq*8;
            const float4 a = *(const float4*)s, b = *(const float4*)(s + 4);
            v[0]=a.x; v[1]=a.y; v[2]=a.z; v[3]=a.w;
            v[4]=b.x; v[5]=b.y; v[6]=b.z; v[7]=b.w;
        }
    }
    union { bf16_t h[8]; uint4 q; } pk;
    #pragma unroll
    for (int j = 0; j < 8; ++j) pk.h[j] = (bf16_t)v[j];
    ((uint4*)ws)[(size_t)wid * 64 + lane] = pk.q;   // dst = brick*1024 + lane*16
}

// =========================== main fused kernel ===========================
__global__ __launch_bounds__(512, 2)
void fused_mlp(const unsigned char* __restrict__ ws,
               const float* __restrict__ b0, const float* __restrict__ b1,
               const float* __restrict__ b2, float* __restrict__ out)
{
    // h bricks 16 KB + h2 bricks 16 KB, wave-private slices. No barriers.
    __shared__ __align__(16) unsigned char hsm[16384];
    __shared__ __align__(16) unsigned char h2sm[16384];

    const int tid  = threadIdx.x;
    const int w    = tid >> 6;         // wave 0..7: owns 16-row slice nt = w
    const int lane = tid & 63;
    const int lr = lane & 15, lq = lane >> 4;
    const int g  = blockIdx.x;         // batch group: bt = g*8 + s
    const int t  = blockIdx.y;         // variable index

    // ---- weights: global -> registers (L2-hit, coalesced 1 KB/instr) ----
    const unsigned char* w0p = ws + W0B_OFF + (size_t)t*16384 + lane*16;
    const unsigned char* w1p = ws + W1B_OFF + (size_t)t*8192  + lane*16;
    const unsigned char* w2p = ws + W2B_OFF + (size_t)t*2048  + lane*16;
    bf16x8 w0f[4][4], w1f[4][2], w2f[2];
    #pragma unroll
    for (int it = 0; it < 4; ++it)
        #pragma unroll
        for (int ks = 0; ks < 4; ++ks)
            w0f[it][ks] = *(const bf16x8*)(w0p + (it*4+ks)*1024);
    #pragma unroll
    for (int it = 0; it < 4; ++it)
        #pragma unroll
        for (int ks = 0; ks < 2; ++ks)
            w1f[it][ks] = *(const bf16x8*)(w1p + (it*2+ks)*1024);
    #pragma unroll
    for (int ks = 0; ks < 2; ++ks)
        w2f[ks] = *(const bf16x8*)(w2p + ks*1024);

    // ---- biases: per-quad float4 (acc-init form) ----
    f32x4 b0q[4], b1q[4];
    #pragma unroll
    for (int it = 0; it < 4; ++it) {
        b0q[it] = *(const f32x4*)(b0 + t*64 + it*16 + lq*4);
        b1q[it] = *(const f32x4*)(b1 + t*64 + it*16 + lq*4);
    }
    const float2 b2v = *(const float2*)(b2 + t*2);

    // ---- x fragments (wave slice nt=w); preload iter 0 ----
    const unsigned char* xp = ws + XB_OFF + lane*16;
    bf16x8 xf[4];
    #pragma unroll
    for (int ks = 0; ks < 4; ++ks)
        xf[ks] = *(const bf16x8*)(xp + (size_t)(((g*8 + 0)*8 + w)*4 + ks)*1024);

    // LDS base offsets for this wave's bricks (within-brick pos is the same
    // for h and h2):  write pos = ((( it&1)*2 + lq>>1)*16 + lr)*16 + (lq&1)*8
    const int wboff = (((lq >> 1) * 16 + lr) * 16) + (lq & 1) * 8;  // it&1 == 0 part

    for (int s = 0; s < 8; ++s) {
        const int bt = g*8 + s;

        // ============ layer 0: D0[i][row] = w0m @ x^T (+b0 via C-init) ============
        f32x4 acc[4];
        #pragma unroll
        for (int it = 0; it < 4; ++it) acc[it] = b0q[it];

        #pragma unroll
        for (int ks = 0; ks < 4; ++ks)
            #pragma unroll
            for (int it = 0; it < 4; ++it)
                acc[it] = __builtin_amdgcn_mfma_f32_16x16x32_bf16(
                              w0f[it][ks], xf[ks], acc[it], 0, 0, 0);

        // ---- xf now dead: prefetch next iter's fragments into the same regs ----
        {
            const int btn = (s < 7) ? bt + 1 : bt;
            #pragma unroll
            for (int ks = 0; ks < 4; ++ks)
                xf[ks] = *(const bf16x8*)(xp + (size_t)((btn*8 + w)*4 + ks)*1024);
        }

        // epi0 -> h bricks: C reg r is k = it*16 + lq*4 + r -> one b64 per it
        #pragma unroll
        for (int it = 0; it < 4; ++it) {
            union { bf16_t h[4]; unsigned long long u; } pk;
            #pragma unroll
            for (int r = 0; r < 4; ++r) {
                float u = acc[it][r];
                pk.h[r] = (bf16_t)fmaxf(u, LEAKY * u);
            }
            int off = (w*2 + (it>>1)) * 1024 + (it&1) * 512 + wboff;
            *(unsigned long long*)(hsm + off) = pk.u;
        }

        // ============ layer 1: D1[i2][row] = w1 @ h^T (+b1 via C-init) ============
        bf16x8 hf[2];
        #pragma unroll
        for (int ks = 0; ks < 2; ++ks)
            hf[ks] = *(const bf16x8*)(hsm + (w*2 + ks)*1024 + lane*16);

        #pragma unroll
        for (int it = 0; it < 4; ++it) acc[it] = b1q[it];   // reuse acc regs

        #pragma unroll
        for (int ks = 0; ks < 2; ++ks)
            #pragma unroll
            for (int it = 0; it < 4; ++it)
                acc[it] = __builtin_amdgcn_mfma_f32_16x16x32_bf16(
                              w1f[it][ks], hf[ks], acc[it], 0, 0, 0);

        // epi1 -> h2 bricks (separate region: no WAR on this wave's h reads)
        #pragma unroll
        for (int it = 0; it < 4; ++it) {
            union { bf16_t h[4]; unsigned long long u; } pk;
            #pragma unroll
            for (int r = 0; r < 4; ++r) {
                float u = acc[it][r];
                pk.h[r] = (bf16_t)fmaxf(u, LEAKY * u);
            }
            int off = (w*2 + (it>>1)) * 1024 + (it&1) * 512 + wboff;
            *(unsigned long long*)(h2sm + off) = pk.u;
        }

        // ============ layer 2: D2[o][row] = w2pad @ h2^T ============
        bf16x8 h2f[2];
        #pragma unroll
        for (int ks = 0; ks < 2; ++ks)
            h2f[ks] = *(const bf16x8*)(h2sm + (w*2 + ks)*1024 + lane*16);

        f32x4 acc2 = (f32x4){0.f, 0.f, 0.f, 0.f};
        #pragma unroll
        for (int ks = 0; ks < 2; ++ks)
            acc2 = __builtin_amdgcn_mfma_f32_16x16x32_bf16(
                       w2f[ks], h2f[ks], acc2, 0, 0, 0);

        // store: o=0,1 live in quad 0, regs 0,1 -> 8B per batch row
        if (lq == 0) {
            int row = bt*128 + w*16 + lr;
            float2 o2 = { acc2[0] + b2v.x, acc2[1] + b2v.y };
            *(float2*)(out + (size_t)row*256 + t*2) = o2;
        }
    }
}

extern "C" void kernel_launch(void* const* d_in, const int* in_sizes, int n_in,
                              void* d_out, int out_size, void* d_ws, size_t ws_size,
                              hipStream_t stream) {
    const float* x  = (const float*)d_in[0];
    const float* w0 = (const float*)d_in[1];
    const float* w1 = (const float*)d_in[2];
    const float* w2 = (const float*)d_in[3];
    const float* b0 = (const float*)d_in[4];
    const float* b1 = (const float*)d_in[5];
    const float* b2 = (const float*)d_in[6];
    unsigned char* ws = (unsigned char*)d_ws;   // needs 5376 KiB
    float* out = (float*)d_out;

    brickify<<<dim3(1344), dim3(256), 0, stream>>>(x, w0, w1, w2, ws);
    // grid (8 batch-groups, 128 t), 512-thread blocks (8 waves x 16 rows).
    fused_mlp<<<dim3(8, 128), dim3(512), 0, stream>>>(ws, b0, b1, b2, out);
}

// Round 5
// 113.299 us; speedup vs baseline: 1.0063x; 1.0063x over previous
//
#include <hip/hip_runtime.h>

// BaseModel_3100966387783 — per-variable masked 3-layer MLP, b=8192, D=128, h=64, o=2.
//
// R5: brick layout + register-resident weights + persistent bt-loop (see R4), plus:
//   - L2 (64->2) computed as direct VALU dot on acc1 registers + __shfl_xor
//     reduce over the 4 quads (no MFMA, no second LDS round-trip, h2 stays fp32)
//   - the single remaining h round-trip is software-pipelined: hf(s) reads are
//     issued after writing h(s) and consumed after L0(s+1)'s 16 MFMAs (~300 cyc)
//   - single h buffer (DS pipe is in-order per wave), zero barriers
// brick = 1 KB = 64 lanes x 16 B bf16; lane l holds
//   T[tile*16 + (l&15)][ks*32 + (l>>4)*8 + 0..7]  (one MFMA A/B fragment).

typedef __bf16 bf16_t;
typedef __bf16 bf16x8 __attribute__((ext_vector_type(8)));
typedef float  f32x4  __attribute__((ext_vector_type(4)));

#define LEAKY 0.01f

// ---------------- ws brick regions (byte offsets) ----------------
#define XB_OFF   0u                  // x bricks:   64 bt x 8 nt x 4 ks = 2048 bricks
#define W0B_OFF  (2048u*1024u)       // w0 masked: 128 t x 4 it x 4 ks = 2048
#define W1B_OFF  (4096u*1024u)       // w1:        128 t x 4 it x 2 ks = 1024
// total ws need: 5120 KiB

// =================== pre-kernel: fp32 -> bf16 brick-ify ===================
__global__ __launch_bounds__(256)
void brickify(const float* __restrict__ x,  const float* __restrict__ w0,
              const float* __restrict__ w1, unsigned char* __restrict__ ws)
{
    const int wid  = blockIdx.x * 4 + (threadIdx.x >> 6);  // one wave = one brick
    const int lane = threadIdx.x & 63;
    const int lr = lane & 15, lq = lane >> 4;

    float v[8];
    if (wid < 2048) {                        // ---- x bricks ----
        int bt = wid >> 5, rem = wid & 31, nt = rem >> 2, ks = rem & 3;
        const float* s = x + (size_t)(bt*128 + nt*16 + lr) * 128 + ks*32 + lq*8;
        const float4 a = *(const float4*)s, b = *(const float4*)(s + 4);
        v[0]=a.x; v[1]=a.y; v[2]=a.z; v[3]=a.w;
        v[4]=b.x; v[5]=b.y; v[6]=b.z; v[7]=b.w;
    } else if (wid < 4096) {                 // ---- w0 bricks (masked j==t -> 0) ----
        int u = wid - 2048, t = u >> 4, rem = u & 15, it = rem >> 2, ks = rem & 3;
        int k0 = ks*32 + lq*8;
        const float* s = w0 + (size_t)(t*64 + it*16 + lr) * 128 + k0;
        const float4 a = *(const float4*)s, b = *(const float4*)(s + 4);
        v[0]=a.x; v[1]=a.y; v[2]=a.z; v[3]=a.w;
        v[4]=b.x; v[5]=b.y; v[6]=b.z; v[7]=b.w;
        #pragma unroll
        for (int j = 0; j < 8; ++j) if (k0 + j == t) v[j] = 0.f;
    } else {                                 // ---- w1 bricks ----
        int u = wid - 4096, t = u >> 3, rem = u & 7, it = rem >> 1, ks = rem & 1;
        const float* s = w1 + (size_t)(t*64 + it*16 + lr) * 64 + ks*32 + lq*8;
        const float4 a = *(const float4*)s, b = *(const float4*)(s + 4);
        v[0]=a.x; v[1]=a.y; v[2]=a.z; v[3]=a.w;
        v[4]=b.x; v[5]=b.y; v[6]=b.z; v[7]=b.w;
    }
    union { bf16_t h[8]; uint4 q; } pk;
    #pragma unroll
    for (int j = 0; j < 8; ++j) pk.h[j] = (bf16_t)v[j];
    ((uint4*)ws)[(size_t)wid * 64 + lane] = pk.q;   // dst = brick*1024 + lane*16
}

// =========================== main fused kernel ===========================
__global__ __launch_bounds__(512, 2)
void fused_mlp(const unsigned char* __restrict__ ws,
               const float* __restrict__ w2,
               const float* __restrict__ b0, const float* __restrict__ b1,
               const float* __restrict__ b2, float* __restrict__ out)
{
    // h bricks only: 8 waves x 2 bricks, wave-private, single-buffered.
    __shared__ __align__(16) unsigned char hsm[16384];

    const int tid  = threadIdx.x;
    const int w    = tid >> 6;         // wave 0..7: owns 16-row slice nt = w
    const int lane = tid & 63;
    const int lr = lane & 15, lq = lane >> 4;
    const int g  = blockIdx.x;         // batch group: bt = g*8 + s
    const int t  = blockIdx.y;         // variable index

    // ---- w0/w1 fragments: global -> registers (L2-hit, 1 KB/instr) ----
    const unsigned char* w0p = ws + W0B_OFF + (size_t)t*16384 + lane*16;
    const unsigned char* w1p = ws + W1B_OFF + (size_t)t*8192  + lane*16;
    bf16x8 w0f[4][4], w1f[4][2];
    #pragma unroll
    for (int it = 0; it < 4; ++it)
        #pragma unroll
        for (int ks = 0; ks < 4; ++ks)
            w0f[it][ks] = *(const bf16x8*)(w0p + (it*4+ks)*1024);
    #pragma unroll
    for (int it = 0; it < 4; ++it)
        #pragma unroll
        for (int ks = 0; ks < 2; ++ks)
            w1f[it][ks] = *(const bf16x8*)(w1p + (it*2+ks)*1024);

    // ---- w2 as per-thread fp32 scalars in C-layout: w2v[o][it][r] ----
    f32x4 w2v[2][4];
    #pragma unroll
    for (int o = 0; o < 2; ++o)
        #pragma unroll
        for (int it = 0; it < 4; ++it)
            w2v[o][it] = *(const f32x4*)(w2 + t*128 + o*64 + it*16 + lq*4);

    // ---- biases ----
    f32x4 b0q[4], b1q[4];
    #pragma unroll
    for (int it = 0; it < 4; ++it) {
        b0q[it] = *(const f32x4*)(b0 + t*64 + it*16 + lq*4);
        b1q[it] = *(const f32x4*)(b1 + t*64 + it*16 + lq*4);
    }
    const float2 b2v = *(const float2*)(b2 + t*2);

    // ---- x fragments (wave slice nt=w); preload iter 0 ----
    const unsigned char* xp = ws + XB_OFF + lane*16;
    bf16x8 xf[4];
    #pragma unroll
    for (int ks = 0; ks < 4; ++ks)
        xf[ks] = *(const bf16x8*)(xp + (size_t)((g*8*8 + w)*4 + ks)*1024);

    const int wboff = ((lq >> 1) * 16 + lr) * 16 + (lq & 1) * 8;

    bf16x8 hf[2];        // h fragments of tile s-1 (read at end of iter s-1)
    f32x4  acc1[4];      // L1 accumulator of tile s-1

    #pragma unroll
    for (int s = 0; s <= 8; ++s) {
        const int bt = g*8 + s;

        f32x4 acc0[4];
        if (s < 8) {
            // ======== layer 0, tile s: D0[i][row] = w0m @ x^T (+b0) ========
            #pragma unroll
            for (int it = 0; it < 4; ++it) acc0[it] = b0q[it];
            #pragma unroll
            for (int ks = 0; ks < 4; ++ks)
                #pragma unroll
                for (int it = 0; it < 4; ++it)
                    acc0[it] = __builtin_amdgcn_mfma_f32_16x16x32_bf16(
                                   w0f[it][ks], xf[ks], acc0[it], 0, 0, 0);
            // xf dead: prefetch tile s+1
            if (s < 7) {
                #pragma unroll
                for (int ks = 0; ks < 4; ++ks)
                    xf[ks] = *(const bf16x8*)(xp + (size_t)(((bt+1)*8 + w)*4 + ks)*1024);
            }
        }

        if (s > 0) {
            // ======== layer 1, tile s-1: hf read last iter, latency hidden ========
            #pragma unroll
            for (int it = 0; it < 4; ++it) acc1[it] = b1q[it];
            #pragma unroll
            for (int ks = 0; ks < 2; ++ks)
                #pragma unroll
                for (int it = 0; it < 4; ++it)
                    acc1[it] = __builtin_amdgcn_mfma_f32_16x16x32_bf16(
                                   w1f[it][ks], hf[ks], acc1[it], 0, 0, 0);
        }

        if (s < 8) {
            // ======== epi0: leaky+cvt -> h bricks; then issue hf(s) reads ========
            #pragma unroll
            for (int it = 0; it < 4; ++it) {
                union { bf16_t h[4]; unsigned long long u; } pk;
                #pragma unroll
                for (int r = 0; r < 4; ++r) {
                    float u = acc0[it][r];
                    pk.h[r] = (bf16_t)fmaxf(u, LEAKY * u);
                }
                int off = (w*2 + (it>>1)) * 1024 + (it&1) * 512 + wboff;
                *(unsigned long long*)(hsm + off) = pk.u;
            }
            // in-order DS pipe: these reads see the writes above; data lands
            // during next iteration's L0 MFMA burst.
            #pragma unroll
            for (int ks = 0; ks < 2; ++ks)
                hf[ks] = *(const bf16x8*)(hsm + (w*2 + ks)*1024 + lane*16);
        }

        if (s > 0) {
            // ======== layer 2, tile s-1: direct dot on acc1 + quad reduce ========
            float p0 = 0.f, p1 = 0.f;
            #pragma unroll
            for (int it = 0; it < 4; ++it)
                #pragma unroll
                for (int r = 0; r < 4; ++r) {
                    float u = acc1[it][r];
                    u = fmaxf(u, LEAKY * u);            // h2 stays fp32
                    p0 = fmaf(w2v[0][it][r], u, p0);
                    p1 = fmaf(w2v[1][it][r], u, p1);
                }
            p0 += __shfl_xor(p0, 16); p0 += __shfl_xor(p0, 32);
            p1 += __shfl_xor(p1, 16); p1 += __shfl_xor(p1, 32);
            if (lq == 0) {
                int row = (bt - 1)*128 + w*16 + lr;
                float2 o2 = { p0 + b2v.x, p1 + b2v.y };
                *(float2*)(out + (size_t)row*256 + t*2) = o2;
            }
        }
    }
}

extern "C" void kernel_launch(void* const* d_in, const int* in_sizes, int n_in,
                              void* d_out, int out_size, void* d_ws, size_t ws_size,
                              hipStream_t stream) {
    const float* x  = (const float*)d_in[0];
    const float* w0 = (const float*)d_in[1];
    const float* w1 = (const float*)d_in[2];
    const float* w2 = (const float*)d_in[3];
    const float* b0 = (const float*)d_in[4];
    const float* b1 = (const float*)d_in[5];
    const float* b2 = (const float*)d_in[6];
    unsigned char* ws = (unsigned char*)d_ws;   // needs 5120 KiB
    float* out = (float*)d_out;

    // 5120 bricks, one wave each, 4 waves/block
    brickify<<<dim3(1280), dim3(256), 0, stream>>>(x, w0, w1, ws);
    // grid (8 batch-groups, 128 t), 512-thread blocks (8 waves x 16 rows).
    fused_mlp<<<dim3(8, 128), dim3(512), 0, stream>>>(ws, w2, b0, b1, b2, out);
}